// Round 11
// baseline (1130.645 us; speedup 1.0000x reference)
//
#include <hip/hip_runtime.h>
#include <math.h>

// PLRNN forward via MFMA matvec, 16-wave TLP variant.
// 256 batches x 1024 steps, 1 WG (1024 thr, 16 waves = 4/SIMD) per batch,
// 1 per CU. Hypothesis: prior 8-wave kernels are latency-bound (MFMA pipe
// ~18cy/op invariant, 2 waves/SIMD can't hide it); 4 waves/SIMD doubles
// stream parallelism on every pipe.
// Per step (2 barriers):
//   p1 (M-split): wave w -> pre rows [32w,32w+32): 2mt x 4kt = 8 MFMA (C-in 0).
//   bounce: masked r15==0: relu(acc1 + h2) -> rt[32w..32w+32) f16, 2 ops.
//   p2 (K-split = OWN rows): br = 1 half8 read of rt[32w..32w+32) (wave-local,
//       no barrier); acc2[mt] = mfma(w1f[mt], br, 0), 8 independent MFMA.
//   pwrite: sel-tree (30 cndmask) -> 2 scalar f32 -> part[z*17 + colrot],
//       colrot = (w + (z>>5)) & 15 (bank-spread + per-row bijective). B1.
//   reduce (dup-8 lanes, i8 = l&7): lane reads part cols {2i8, 2i8+1} of its
//       row0 = 8w + (l>>3), adds C[row0,2i8..]*s (f32) + h1 (i8==0), then
//       xor1 + xor2 quad-perm DPP + ROW_HALF_MIRROR DPP -> u, all-VALU.
//   update: zn = A*zf + u; TF via Xc (waves<8); publish zf_h + outc. B2.
// X/S/out staged in LDS per 128-step chunk -> no global ops in steady state.

#define NB 256
#define T  1024
#define DX 64
#define DZ 128
#define DH 512
#define DS 16
#define CHUNK 128
#define PSTR 17

typedef _Float16 half8 __attribute__((ext_vector_type(8)));
typedef _Float16 v4h   __attribute__((ext_vector_type(4)));
typedef float    f32x4 __attribute__((ext_vector_type(4)));

__device__ __forceinline__ half8 cvt8(const float* __restrict__ src) {
  const float4 a = *reinterpret_cast<const float4*>(src);
  const float4 c = *reinterpret_cast<const float4*>(src + 4);
  half8 h;
  h[0] = (_Float16)a.x; h[1] = (_Float16)a.y; h[2] = (_Float16)a.z; h[3] = (_Float16)a.w;
  h[4] = (_Float16)c.x; h[5] = (_Float16)c.y; h[6] = (_Float16)c.z; h[7] = (_Float16)c.w;
  return h;
}

template <int CTRL>
__device__ __forceinline__ float dpp_add(float v) {   // v + v[dpp-mapped lane]
  const int t = __builtin_amdgcn_update_dpp(0, __float_as_int(v), CTRL, 0xF, 0xF, true);
  return v + __int_as_float(t);
}

__device__ __forceinline__ f32x4 sel4(int c, f32x4 a, f32x4 b) {   // c ? a : b
  f32x4 r;
  r[0] = c ? a[0] : b[0];  r[1] = c ? a[1] : b[1];
  r[2] = c ? a[2] : b[2];  r[3] = c ? a[3] : b[3];
  return r;
}

__global__ __launch_bounds__(1024, 4) void plrnn_kernel(
    const float* __restrict__ X, const float* __restrict__ S,
    const float* __restrict__ A, const float* __restrict__ W1,
    const float* __restrict__ W2, const float* __restrict__ h1,
    const float* __restrict__ h2, const float* __restrict__ C,
    float* __restrict__ out)
{
  __shared__ __align__(16) _Float16 zf_h[DZ];          // 256 B
  __shared__ __align__(16) _Float16 rt[DH];            // 1 KiB: relu(pre) f16
  __shared__ __align__(16) float    part[DZ * PSTR];   // 8.5 KiB
  __shared__ __align__(16) float    Xc[CHUNK][DX];     // 32 KiB: X[t+1 .. t+128]
  __shared__ __align__(16) float    Sc[CHUNK][DS];     // 8 KiB:  S[t .. t+127]
  __shared__ __align__(16) float    outc[CHUNK][DX];   // 32 KiB

  const int b    = blockIdx.x;
  const int tid  = threadIdx.x;
  const int w    = tid >> 6;           // wave 0..15
  const int l    = tid & 63;
  const int g    = l >> 4;             // 16-lane group (B k-slice / D row-block)
  const int r15  = l & 15;             // A row-in-tile / D col
  const int i8   = l & 7;              // dup-8 reduce index
  const int row0 = 8 * w + (l >> 3);   // this lane's state row (dup x8)
  const int m    = r15 & 7;            // pwrite: source tile
  const int jp   = r15 >> 3;           // pwrite: j parity

  // ---- one-time: stage chunk 0 (X rows 1..128 clamped, S rows 0..127) ----
  {
    #pragma unroll
    for (int k = 0; k < 2; ++k) {
      const int flat = k * 4096 + tid * 4;
      int srow = 1 + (flat >> 6);
      if (srow > T - 1) srow = T - 1;
      const float4 v = *reinterpret_cast<const float4*>(X + ((size_t)b * T + srow) * DX + (flat & 63));
      *reinterpret_cast<float4*>(&((float*)Xc)[flat]) = v;
    }
    if (tid < 512) {
      const int flat = tid * 4;
      const float4 v = *reinterpret_cast<const float4*>(S + ((size_t)b * T) * DS + flat);
      *reinterpret_cast<float4*>(&((float*)Sc)[flat]) = v;
    }
  }

  // ---- one-time: W2 A-fragments (wave w: rows 32w+16mt+r15, k=32kt+8g+e) ----
  half8 w2f[2][4];
  #pragma unroll
  for (int mt = 0; mt < 2; ++mt)
    #pragma unroll
    for (int kt = 0; kt < 4; ++kt)
      w2f[mt][kt] = cvt8(W2 + ((size_t)b * DH + 32 * w + 16 * mt + r15) * DZ + 32 * kt + 8 * g);

  // ---- one-time: W1 A-fragments (rows 16mt+r15, k = 32w+8g+e: OWN k-slice) ----
  half8 w1f[8];
  #pragma unroll
  for (int mt = 0; mt < 8; ++mt)
    w1f[mt] = cvt8(W1 + ((size_t)b * DZ + 16 * mt + r15) * DH + 32 * w + 8 * g);

  // ---- one-time: h2 rows 32w+16mt+4g+j, f16-packed (added at bounce) ----
  v4h h2pk[2];
  #pragma unroll
  for (int mt = 0; mt < 2; ++mt) {
    const f32x4 hv = *reinterpret_cast<const f32x4*>(h2 + (size_t)b * DH + 32 * w + 16 * mt + 4 * g);
    #pragma unroll
    for (int j = 0; j < 4; ++j) h2pk[mt][j] = (_Float16)hv[j];
  }

  // ---- one-time: per-lane reduce/update constants (row0, dup x8) ----
  const float Areg  = A[(size_t)b * DZ + row0];
  const float h1reg = h1[(size_t)b * DZ + row0];
  const float Cp0   = C[((size_t)b * DZ + row0) * DS + 2 * i8];
  const float Cp1   = C[((size_t)b * DZ + row0) * DS + 2 * i8 + 1];
  float zfcur = 0.f;
  if (row0 < DX) {
    const float x0 = X[((size_t)b * T) * DX + row0];
    zfcur = (x0 != x0) ? 0.f : x0;     // zf(0) = TF(TF(0,X0,1), X0, 1/8) = x0
  }
  if (i8 == 0) zf_h[row0] = (_Float16)zfcur;
  __syncthreads();

  const f32x4 zero4 = {0.f, 0.f, 0.f, 0.f};

  for (int t = 0; t < T; ++t) {
    // ---- chunk boundary: flush out-chunk, stage next X/S chunk ----
    if ((t & (CHUNK - 1)) == 0 && t) {
      const int c0 = t - CHUNK;
      #pragma unroll
      for (int k = 0; k < 2; ++k) {
        const int flat = k * 4096 + tid * 4;
        const float4 v = *reinterpret_cast<const float4*>(&((float*)outc)[flat]);
        *reinterpret_cast<float4*>(out + ((size_t)b * T + c0) * DX + flat) = v;
      }
      #pragma unroll
      for (int k = 0; k < 2; ++k) {
        const int flat = k * 4096 + tid * 4;
        int srow = t + 1 + (flat >> 6);
        if (srow > T - 1) srow = T - 1;
        const float4 v = *reinterpret_cast<const float4*>(X + ((size_t)b * T + srow) * DX + (flat & 63));
        *reinterpret_cast<float4*>(&((float*)Xc)[flat]) = v;
      }
      if (tid < 512) {
        const int flat = tid * 4;
        const float4 v = *reinterpret_cast<const float4*>(S + ((size_t)b * T + t) * DS + flat);
        *reinterpret_cast<float4*>(&((float*)Sc)[flat]) = v;
      }
      __syncthreads();
    }
    const int tc = t & (CHUNK - 1);

    // ---- phase 1: pre-part = W2·zf (8 MFMA, 2 chains of depth 4) ----
    half8 bz[4];
    #pragma unroll
    for (int kt = 0; kt < 4; ++kt)
      bz[kt] = *reinterpret_cast<const half8*>(zf_h + 32 * kt + 8 * g);

    f32x4 acc1[2];
    #pragma unroll
    for (int mt = 0; mt < 2; ++mt)
      acc1[mt] = __builtin_amdgcn_mfma_f32_16x16x32_f16(w2f[mt][0], bz[0], zero4, 0, 0, 0);
    #pragma unroll
    for (int kt = 1; kt < 4; ++kt)
      #pragma unroll
      for (int mt = 0; mt < 2; ++mt)
        acc1[mt] = __builtin_amdgcn_mfma_f32_16x16x32_f16(w2f[mt][kt], bz[kt], acc1[mt], 0, 0, 0);

    // ---- bounce (masked): relu(acc1 + h2) -> rt[32w..32w+32) f16 ----
    if (r15 == 0) {
      #pragma unroll
      for (int mt = 0; mt < 2; ++mt) {
        v4h p;
        #pragma unroll
        for (int j = 0; j < 4; ++j)
          p[j] = (_Float16)fmaxf(acc1[mt][j] + (float)h2pk[mt][j], 0.f);
        *reinterpret_cast<v4h*>(&rt[32 * w + 16 * mt + 4 * g]) = p;
      }
    }

    // ---- phase 2 (K-split = own rows, wave-local, no barrier needed) ----
    const half8 br = *reinterpret_cast<const half8*>(rt + 32 * w + 8 * g);
    f32x4 acc2[8];
    #pragma unroll
    for (int mt = 0; mt < 8; ++mt)
      acc2[mt] = __builtin_amdgcn_mfma_f32_16x16x32_f16(w1f[mt], br, zero4, 0, 0, 0);

    // ---- pwrite: sel-tree -> 2 scalar f32, column-rotated bank spread ----
    {
      const f32x4 s01 = sel4(r15 & 1, acc2[1], acc2[0]);
      const f32x4 s23 = sel4(r15 & 1, acc2[3], acc2[2]);
      const f32x4 s45 = sel4(r15 & 1, acc2[5], acc2[4]);
      const f32x4 s67 = sel4(r15 & 1, acc2[7], acc2[6]);
      const f32x4 a03 = sel4(r15 & 2, s23, s01);
      const f32x4 a47 = sel4(r15 & 2, s67, s45);
      const f32x4 q   = sel4(r15 & 4, a47, a03);
      const float v1  = jp ? q[1] : q[0];
      const float v2  = jp ? q[3] : q[2];
      const int z1 = 16 * m + 4 * g + jp;       // row of v1; v2 -> z1+2
      const int z2 = z1 + 2;
      part[z1 * PSTR + ((w + (z1 >> 5)) & 15)] = v1;
      part[z2 * PSTR + ((w + (z2 >> 5)) & 15)] = v2;
    }
    __syncthreads();   // B1: partials visible

    // ---- reduce (dup-8): 2 part reads + C·s + h1, then 3 DPP adds ----
    const float p0 = part[row0 * PSTR + 2 * i8];
    const float p1 = part[row0 * PSTR + 2 * i8 + 1];
    const float2 s2 = *reinterpret_cast<const float2*>(&Sc[tc][2 * i8]);
    float u = p0 + p1 + Cp0 * s2.x + Cp1 * s2.y + ((i8 == 0) ? h1reg : 0.f);
    u = dpp_add<0xB1>(u);     // quad_perm(1,0,3,2): lane^1
    u = dpp_add<0x4E>(u);     // quad_perm(2,3,0,1): lane^2
    u = dpp_add<0x141>(u);    // row_half_mirror: lane^{...} across 4-lane halves of 8

    // ---- update (per-lane f32 state, dup x8) ----
    const float zn = Areg * zfcur + u;
    float zfn = zn;
    if (w < 8) {                       // rows < 64: teacher forcing + output
      const float x = Xc[tc][row0];
      zfn = (x != x) ? zn : (0.125f * x + 0.875f * zn);
      if (i8 == 0) outc[tc][row0] = zn;
    }
    zfcur = zfn;
    if (i8 == 0) zf_h[row0] = (_Float16)zfn;
    __syncthreads();   // B2: zf(t+1) visible
  }

  // ---- final flush (last chunk) ----
  {
    const int c0 = T - CHUNK;
    #pragma unroll
    for (int k = 0; k < 2; ++k) {
      const int flat = k * 4096 + tid * 4;
      const float4 v = *reinterpret_cast<const float4*>(&((float*)outc)[flat]);
      *reinterpret_cast<float4*>(out + ((size_t)b * T + c0) * DX + flat) = v;
    }
  }
}

extern "C" void kernel_launch(void* const* d_in, const int* in_sizes, int n_in,
                              void* d_out, int out_size, void* d_ws, size_t ws_size,
                              hipStream_t stream) {
  const float* X  = (const float*)d_in[0];
  const float* S  = (const float*)d_in[1];
  const float* A  = (const float*)d_in[2];
  const float* W1 = (const float*)d_in[3];
  const float* W2 = (const float*)d_in[4];
  const float* h1 = (const float*)d_in[5];
  const float* h2 = (const float*)d_in[6];
  const float* C  = (const float*)d_in[7];
  float* out = (float*)d_out;
  plrnn_kernel<<<dim3(NB), dim3(1024), 0, stream>>>(X, S, A, W1, W2, h1, h2, C, out);
}